// Round 1
// baseline (32095.197 us; speedup 1.0000x reference)
//
#include <hip/hip_runtime.h>
#include <math.h>

#define B_   256
#define T_   256
#define IND  64
#define HID_ 1024
#define D2   512
#define G3   3072

__device__ __forceinline__ float sigmoidf_(float x) {
    return __fdividef(1.0f, 1.0f + __expf(-x));
}
__device__ __forceinline__ float tanhf_(float x) {
    // tanh(x) = 1 - 2/(1+e^{2x}); saturates correctly for |x| large (no NaN)
    return 1.0f - __fdividef(2.0f, 1.0f + __expf(2.0f * x));
}

// ---------------- prelim: W2 = fc2_w @ fc1_w, b2 = fc2_w@fc1_b + fc2_b ----
__global__ __launch_bounds__(256) void k_w2(
    const float* __restrict__ fc2_w, const float* __restrict__ fc1_w,
    const float* __restrict__ fc1_b, const float* __restrict__ fc2_b,
    float* __restrict__ W2, float* __restrict__ b2)
{
    int idx = blockIdx.x * 256 + threadIdx.x;   // 0..65535
    int r = idx >> 6, c = idx & 63;
    float acc = 0.f;
    for (int k = 0; k < D2; ++k)
        acc += fc2_w[(size_t)r * D2 + k] * fc1_w[(size_t)k * IND + c];
    W2[idx] = acc;
    if (c == 0) {
        float a = fc2_b[r];
        for (int k = 0; k < D2; ++k)
            a += fc2_w[(size_t)r * D2 + k] * fc1_b[k];
        b2[r] = a;
    }
}

// ---------------- prelim: Wc = w_ih @ W2, bc = w_ih@b2 + b_ih -------------
__global__ __launch_bounds__(256) void k_wc(
    const float* __restrict__ w_ih, const float* __restrict__ W2,
    const float* __restrict__ b2, const float* __restrict__ b_ih,
    float* __restrict__ Wc, float* __restrict__ bc)
{
    int idx = blockIdx.x * 256 + threadIdx.x;   // 0..196607
    int r = idx >> 6, c = idx & 63;
    float acc = 0.f;
    for (int k = 0; k < HID_; ++k)
        acc += w_ih[(size_t)r * HID_ + k] * W2[(size_t)k * IND + c];
    Wc[idx] = acc;
    if (c == 0) {
        float a = b_ih[r];
        for (int k = 0; k < HID_; ++k)
            a += w_ih[(size_t)r * HID_ + k] * b2[k];
        bc[r] = a;
    }
}

// ---------------- main persistent GRU kernel ------------------------------
// 256 blocks x 256 threads. Block g: ct=g&31 (h-col tile of 32), bt=g>>5
// (batch tile of 32). g%8==ct%8 pins each col group to one XCD for w_hh L2
// residency. Barriers are per-bt (32 blocks each) since batch rows never mix.
__global__ __launch_bounds__(256) void k_gru(
    const float* __restrict__ input,   // (256,256,64)
    const float* __restrict__ w_hh,    // (3072,1024)
    const float* __restrict__ b_hh,    // (3072)
    const float* __restrict__ Wc,      // (3072,64)
    const float* __restrict__ bc,      // (3072)
    float* __restrict__ hA,            // h buffer 0 (holds h0 at entry; final h at exit)
    float* __restrict__ hB,            // h buffer 1
    int* __restrict__ bar)             // barrier scratch (zeroed)
{
    const int g   = blockIdx.x;
    const int ct  = g & 31;
    const int bt  = g >> 5;
    const int j0  = ct << 5;
    const int b0  = bt << 5;
    const int tid = threadIdx.x;
    const int jj  = tid & 31;   // local h-col
    const int bq  = tid >> 5;   // 0..7; batches handled: bq + 8*i

    __shared__ float sh_a[32][68];   // h (or x) tile: [local_b][k]
    __shared__ float sh_w[96][68];   // w rows [gate*32+jj][k]

    const float bias_r  = bc[j0 + jj]        + b_hh[j0 + jj];
    const float bias_z  = bc[1024 + j0 + jj] + b_hh[1024 + j0 + jj];
    const float bias_ni = bc[2048 + j0 + jj];
    const float bias_nh = b_hh[2048 + j0 + jj];

    int* arrive  = bar + bt * 128;
    int* release = bar + bt * 128 + 32;

    const int lr = tid >> 4;           // 0..15 (load row)
    const int lc = (tid & 15) << 2;    // 0..60 (load col, float4)

    for (int t = 0; t < T_; ++t) {
        const float* hin  = (t & 1) ? hB : hA;
        float*       hout = (t & 1) ? hA : hB;

        float acc_r[4]  = {0.f, 0.f, 0.f, 0.f};
        float acc_z[4]  = {0.f, 0.f, 0.f, 0.f};
        float acc_ni[4] = {0.f, 0.f, 0.f, 0.f};
        float acc_nh[4] = {0.f, 0.f, 0.f, 0.f};

        // ---- gi phase: x_t (32x64) x Wc-rows (96x64), K=64 ----
        #pragma unroll
        for (int p = 0; p < 2; ++p) {
            int row = lr + (p << 4);
            *(float4*)&sh_a[row][lc] =
                *(const float4*)(input + ((size_t)(b0 + row) * T_ + t) * IND + lc);
        }
        #pragma unroll
        for (int p = 0; p < 6; ++p) {
            int row  = lr + (p << 4);
            int grow = (row >> 5) * HID_ + j0 + (row & 31);
            *(float4*)&sh_w[row][lc] =
                *(const float4*)(Wc + (size_t)grow * IND + lc);
        }
        __syncthreads();
        #pragma unroll
        for (int k = 0; k < IND; k += 4) {
            float4 wr = *(const float4*)&sh_w[jj][k];
            float4 wz = *(const float4*)&sh_w[32 + jj][k];
            float4 wn = *(const float4*)&sh_w[64 + jj][k];
            #pragma unroll
            for (int i = 0; i < 4; ++i) {
                float4 xv = *(const float4*)&sh_a[bq + (i << 3)][k];
                acc_r[i]  += xv.x * wr.x + xv.y * wr.y + xv.z * wr.z + xv.w * wr.w;
                acc_z[i]  += xv.x * wz.x + xv.y * wz.y + xv.z * wz.z + xv.w * wz.w;
                acc_ni[i] += xv.x * wn.x + xv.y * wn.y + xv.z * wn.z + xv.w * wn.w;
            }
        }
        __syncthreads();

        // ---- gh phase: K=1024 in chunks of 64 ----
        for (int kk = 0; kk < HID_; kk += 64) {
            #pragma unroll
            for (int p = 0; p < 2; ++p) {
                int row = lr + (p << 4);
                *(float4*)&sh_a[row][lc] =
                    *(const float4*)(hin + (size_t)(b0 + row) * HID_ + kk + lc);
            }
            #pragma unroll
            for (int p = 0; p < 6; ++p) {
                int row  = lr + (p << 4);
                int grow = (row >> 5) * HID_ + j0 + (row & 31);
                *(float4*)&sh_w[row][lc] =
                    *(const float4*)(w_hh + (size_t)grow * HID_ + kk + lc);
            }
            __syncthreads();
            #pragma unroll
            for (int k = 0; k < 64; k += 4) {
                float4 wr = *(const float4*)&sh_w[jj][k];
                float4 wz = *(const float4*)&sh_w[32 + jj][k];
                float4 wn = *(const float4*)&sh_w[64 + jj][k];
                #pragma unroll
                for (int i = 0; i < 4; ++i) {
                    float4 hv = *(const float4*)&sh_a[bq + (i << 3)][k];
                    acc_r[i]  += hv.x * wr.x + hv.y * wr.y + hv.z * wr.z + hv.w * wr.w;
                    acc_z[i]  += hv.x * wz.x + hv.y * wz.y + hv.z * wz.z + hv.w * wz.w;
                    acc_nh[i] += hv.x * wn.x + hv.y * wn.y + hv.z * wn.z + hv.w * wn.w;
                }
            }
            __syncthreads();
        }

        // ---- gates + h update ----
        #pragma unroll
        for (int i = 0; i < 4; ++i) {
            int b = b0 + bq + (i << 3);
            float hprev = hin[(size_t)b * HID_ + j0 + jj];
            float r = sigmoidf_(acc_r[i] + bias_r);
            float z = sigmoidf_(acc_z[i] + bias_z);
            float n = tanhf_(acc_ni[i] + bias_ni + r * (acc_nh[i] + bias_nh));
            hout[(size_t)b * HID_ + j0 + jj] = (1.0f - z) * n + z * hprev;
        }

        // ---- barrier among the 32 blocks sharing this batch tile ----
        __syncthreads();
        if (tid == 0) {
            int phase = t + 1;
            int old = __hip_atomic_fetch_add(arrive, 1, __ATOMIC_ACQ_REL,
                                             __HIP_MEMORY_SCOPE_AGENT);
            if (old == (phase << 5) - 1) {
                __hip_atomic_store(release, phase, __ATOMIC_RELEASE,
                                   __HIP_MEMORY_SCOPE_AGENT);
            } else {
                while (__hip_atomic_load(release, __ATOMIC_ACQUIRE,
                                         __HIP_MEMORY_SCOPE_AGENT) < phase)
                    __builtin_amdgcn_s_sleep(1);
            }
        }
        __syncthreads();
        __threadfence();
    }
}

// ---------------- fc3: out3 = relu(relu(h) @ fc3_wT + fc3_b) --------------
__global__ __launch_bounds__(256) void k_fc3(
    const float* __restrict__ h, const float* __restrict__ fc3_w,
    const float* __restrict__ fc3_b, float* __restrict__ out3)
{
    const int bt = blockIdx.x >> 3;   // 0..3
    const int dt = blockIdx.x & 7;    // 0..7
    const int b0 = bt << 6;
    const int d0 = dt << 6;
    const int tid = threadIdx.x;
    const int tx = tid & 15, ty = tid >> 4;

    __shared__ float sh_h[64][36];
    __shared__ float sh_w[64][36];

    float acc[4][4] = {};

    const int lr = tid >> 3;          // 0..31
    const int lc = (tid & 7) << 2;    // 0..28

    for (int kk = 0; kk < HID_; kk += 32) {
        #pragma unroll
        for (int p = 0; p < 2; ++p) {
            int row = lr + (p << 5);
            float4 v = *(const float4*)(h + (size_t)(b0 + row) * HID_ + kk + lc);
            v.x = fmaxf(v.x, 0.f); v.y = fmaxf(v.y, 0.f);
            v.z = fmaxf(v.z, 0.f); v.w = fmaxf(v.w, 0.f);
            *(float4*)&sh_h[row][lc] = v;
            *(float4*)&sh_w[row][lc] =
                *(const float4*)(fc3_w + (size_t)(d0 + row) * HID_ + kk + lc);
        }
        __syncthreads();
        #pragma unroll
        for (int k = 0; k < 32; ++k) {
            float hv[4], wv[4];
            #pragma unroll
            for (int i = 0; i < 4; ++i) hv[i] = sh_h[ty + (i << 4)][k];
            #pragma unroll
            for (int q = 0; q < 4; ++q) wv[q] = sh_w[tx + (q << 4)][k];
            #pragma unroll
            for (int i = 0; i < 4; ++i)
                #pragma unroll
                for (int q = 0; q < 4; ++q)
                    acc[i][q] += hv[i] * wv[q];
        }
        __syncthreads();
    }
    #pragma unroll
    for (int i = 0; i < 4; ++i) {
        int b = b0 + ty + (i << 4);
        #pragma unroll
        for (int q = 0; q < 4; ++q) {
            int d = d0 + tx + (q << 4);
            out3[(size_t)b * D2 + d] = fmaxf(acc[i][q] + fc3_b[d], 0.f);
        }
    }
}

// ---------------- copy final h -> hn_out slot of d_out --------------------
__global__ __launch_bounds__(256) void k_copy(
    const float* __restrict__ src, float* __restrict__ dst)
{
    int i = (blockIdx.x * 256 + threadIdx.x) << 2;
    *(float4*)(dst + i) = *(const float4*)(src + i);
}

// ---------------- heads: params[b,o] = out3[b,:]·heads_w[cid[b],o,:]+b ----
__global__ __launch_bounds__(256) void k_heads(
    const float* __restrict__ out3, const int* __restrict__ cult,
    const float* __restrict__ hw, const float* __restrict__ hb,
    float* __restrict__ params)
{
    int b = blockIdx.x;
    int o = threadIdx.x >> 4;   // 0..15
    int l = threadIdx.x & 15;
    int cid = cult[b];
    const float* w = hw + ((size_t)cid * 16 + o) * D2;
    const float* x = out3 + (size_t)b * D2;
    float acc = 0.f;
    #pragma unroll
    for (int m = 0; m < 8; ++m) {
        int d4 = (l + (m << 4)) << 2;
        float4 xv = *(const float4*)(x + d4);
        float4 wv = *(const float4*)(w + d4);
        acc += xv.x * wv.x + xv.y * wv.y + xv.z * wv.z + xv.w * wv.w;
    }
    #pragma unroll
    for (int s = 1; s < 16; s <<= 1)
        acc += __shfl_xor(acc, s, 16);
    if (l == 0)
        params[(size_t)b * 16 + o] = acc + hb[(size_t)cid * 16 + o];
}

extern "C" void kernel_launch(void* const* d_in, const int* in_sizes, int n_in,
                              void* d_out, int out_size, void* d_ws, size_t ws_size,
                              hipStream_t stream)
{
    const float* input = (const float*)d_in[0];
    const float* hn    = (const float*)d_in[1];
    const int*   cult  = (const int*)d_in[2];
    const float* fc1_w = (const float*)d_in[3];
    const float* fc1_b = (const float*)d_in[4];
    const float* fc2_w = (const float*)d_in[5];
    const float* fc2_b = (const float*)d_in[6];
    const float* w_ih  = (const float*)d_in[7];
    const float* w_hh  = (const float*)d_in[8];
    const float* b_ih  = (const float*)d_in[9];
    const float* b_hh  = (const float*)d_in[10];
    const float* fc3_w = (const float*)d_in[11];
    const float* fc3_b = (const float*)d_in[12];
    const float* hw    = (const float*)d_in[13];
    const float* hb    = (const float*)d_in[14];
    float* out = (float*)d_out;

    // workspace layout (floats)
    float* wsf  = (float*)d_ws;
    int*   bar  = (int*)d_ws;            // [0 .. 1024) ints for barriers
    float* W2   = wsf + 1024;            // 1024*64
    float* b2   = W2 + 65536;            // 1024
    float* Wc   = b2 + 1024;             // 3072*64
    float* bc   = Wc + 196608;           // 3072
    float* hA   = bc + 3072;             // 256*1024
    float* hB   = hA + 262144;           // 256*1024
    float* out3 = hB + 262144;           // 256*512

    hipMemsetAsync(d_ws, 0, 4096, stream);
    hipMemcpyAsync(hA, hn, (size_t)262144 * sizeof(float),
                   hipMemcpyDeviceToDevice, stream);

    k_w2<<<256, 256, 0, stream>>>(fc2_w, fc1_w, fc1_b, fc2_b, W2, b2);
    k_wc<<<768, 256, 0, stream>>>(w_ih, W2, b2, b_ih, Wc, bc);
    k_gru<<<256, 256, 0, stream>>>(input, w_hh, b_hh, Wc, bc, hA, hB, bar);
    k_fc3<<<32, 256, 0, stream>>>(hA, fc3_w, fc3_b, out3);
    k_copy<<<256, 256, 0, stream>>>(hA, out + 4096);
    k_heads<<<256, 256, 0, stream>>>(out3, cult, hw, hb, out);
}

// Round 2
// 25706.390 us; speedup vs baseline: 1.2485x; 1.2485x over previous
//
#include <hip/hip_runtime.h>

#define B_   256
#define T_   256
#define IND  64
#define HID_ 1024
#define D2   512

__device__ __forceinline__ float sigmoidf_(float x) {
    return __fdividef(1.0f, 1.0f + __expf(-x));
}
__device__ __forceinline__ float tanhf_(float x) {
    return 1.0f - __fdividef(2.0f, 1.0f + __expf(2.0f * x));
}

// ---- coherent (L1/L2-bypassing) accesses: relaxed SYSTEM-scope atomics ----
// These emit global_load/store with sc0 sc1 -> served at the memory-side L3,
// so cross-XCD visibility needs NO cache-invalidating fences. Weights stay
// cached in L1/L2 untouched for all 256 steps.
__device__ __forceinline__ float cohLoadF(const float* p) {
    return __hip_atomic_load(p, __ATOMIC_RELAXED, __HIP_MEMORY_SCOPE_SYSTEM);
}
__device__ __forceinline__ void cohStoreF(float* p, float v) {
    __hip_atomic_store(p, v, __ATOMIC_RELAXED, __HIP_MEMORY_SCOPE_SYSTEM);
}
union F2U { unsigned long long u; float f[2]; };
__device__ __forceinline__ float4 cohLoad4(const float* p) {
    F2U a, b;
    a.u = __hip_atomic_load((const unsigned long long*)p,       __ATOMIC_RELAXED, __HIP_MEMORY_SCOPE_SYSTEM);
    b.u = __hip_atomic_load(((const unsigned long long*)p) + 1, __ATOMIC_RELAXED, __HIP_MEMORY_SCOPE_SYSTEM);
    return make_float4(a.f[0], a.f[1], b.f[0], b.f[1]);
}

// ---------------- prelim: W2 = fc2_w @ fc1_w, b2 = fc2_w@fc1_b + fc2_b ----
__global__ __launch_bounds__(256) void k_w2(
    const float* __restrict__ fc2_w, const float* __restrict__ fc1_w,
    const float* __restrict__ fc1_b, const float* __restrict__ fc2_b,
    float* __restrict__ W2, float* __restrict__ b2)
{
    int idx = blockIdx.x * 256 + threadIdx.x;   // 0..65535
    int r = idx >> 6, c = idx & 63;
    float acc = 0.f;
    for (int k = 0; k < D2; ++k)
        acc += fc2_w[(size_t)r * D2 + k] * fc1_w[(size_t)k * IND + c];
    W2[idx] = acc;
    if (c == 0) {
        float a = fc2_b[r];
        for (int k = 0; k < D2; ++k)
            a += fc2_w[(size_t)r * D2 + k] * fc1_b[k];
        b2[r] = a;
    }
}

// ---------------- prelim: Wc = w_ih @ W2, bc = w_ih@b2 + b_ih -------------
__global__ __launch_bounds__(256) void k_wc(
    const float* __restrict__ w_ih, const float* __restrict__ W2,
    const float* __restrict__ b2, const float* __restrict__ b_ih,
    float* __restrict__ Wc, float* __restrict__ bc)
{
    int idx = blockIdx.x * 256 + threadIdx.x;   // 0..196607
    int r = idx >> 6, c = idx & 63;
    float acc = 0.f;
    for (int k = 0; k < HID_; ++k)
        acc += w_ih[(size_t)r * HID_ + k] * W2[(size_t)k * IND + c];
    Wc[idx] = acc;
    if (c == 0) {
        float a = b_ih[r];
        for (int k = 0; k < HID_; ++k)
            a += w_ih[(size_t)r * HID_ + k] * b2[k];
        bc[r] = a;
    }
}

// ---------------- main persistent GRU kernel ------------------------------
// 256 blocks x 256 threads, 1 block/CU (resident -> spin barrier is safe,
// proven in round 1). Block g: ct=g&31 (32 h-cols), bt=g>>5 (32 batches).
// g%8 == ct%8 pins each col-group to one XCD: its 1.57 MB w_hh slice stays
// L2-resident because nothing ever invalidates L2 in this kernel.
// Pipelined K-loop: K=32 chunks, LDS double-buffered, 1 sync per chunk.
#define COMPUTE(S, AN)                                                     \
  { _Pragma("unroll")                                                      \
    for (int k = 0; k < 32; k += 4) {                                      \
      const float4 wr = *(const float4*)&bw[S][jj][k];                     \
      const float4 wz = *(const float4*)&bw[S][32 + jj][k];                \
      const float4 wn = *(const float4*)&bw[S][64 + jj][k];                \
      _Pragma("unroll")                                                    \
      for (int i = 0; i < 4; ++i) {                                        \
        const float4 av = *(const float4*)&ba[S][bq + (i << 3)][k];        \
        acc_r[i] += av.x*wr.x + av.y*wr.y + av.z*wr.z + av.w*wr.w;         \
        acc_z[i] += av.x*wz.x + av.y*wz.y + av.z*wz.z + av.w*wz.w;         \
        AN[i]    += av.x*wn.x + av.y*wn.y + av.z*wn.z + av.w*wn.w;         \
      }                                                                    \
    } }

__global__ __launch_bounds__(256) void k_gru(
    const float* __restrict__ input,   // (256,256,64)
    const float* __restrict__ w_hh,    // (3072,1024)
    const float* __restrict__ b_hh,    // (3072)
    const float* __restrict__ Wc,      // (3072,64)
    const float* __restrict__ bc,      // (3072)
    float* __restrict__ hA,            // h buffer 0 (h0 at entry; final h at exit)
    float* __restrict__ hB,            // h buffer 1
    int* __restrict__ bar)             // barrier scratch (zeroed)
{
    const int g   = blockIdx.x;
    const int ct  = g & 31;
    const int bt  = g >> 5;
    const int j0  = ct << 5;
    const int b0  = bt << 5;
    const int tid = threadIdx.x;
    const int jj  = tid & 31;
    const int bq  = tid >> 5;

    __shared__ float bw[2][96][36];   // weight tiles (pad 36: conflict-free)
    __shared__ float ba[2][32][36];   // h/x tiles (reads broadcast across jj)

    const float bias_r  = bc[j0 + jj]        + b_hh[j0 + jj];
    const float bias_z  = bc[1024 + j0 + jj] + b_hh[1024 + j0 + jj];
    const float bias_ni = bc[2048 + j0 + jj];
    const float bias_nh = b_hh[2048 + j0 + jj];

    int* arrive  = bar + bt * 128;        // per-bt group of 32 blocks
    int* release = bar + bt * 128 + 32;   // separate 128B line

    const int lr = tid >> 3;          // 0..31 staging row
    const int lc = (tid & 7) << 2;    // 0,4..28 staging col (float4)

    const float* wp0 = w_hh + (size_t)(       j0 + lr) * HID_ + lc;
    const float* wp1 = w_hh + (size_t)(1024 + j0 + lr) * HID_ + lc;
    const float* wp2 = w_hh + (size_t)(2048 + j0 + lr) * HID_ + lc;
    const float* cp0 = Wc + (size_t)(       j0 + lr) * IND + lc;
    const float* cp1 = Wc + (size_t)(1024 + j0 + lr) * IND + lc;
    const float* cp2 = Wc + (size_t)(2048 + j0 + lr) * IND + lc;
    const float* xrow = input + (size_t)(b0 + lr) * T_ * IND + lc;
    const size_t hrow_off = (size_t)(b0 + lr) * HID_ + lc;

    // stage gi chunks (t=0): Wc rows + x(0) into buf0/buf1
    auto stage_gi = [&](int c, int tt) {
        *(float4*)&bw[c][lr     ][lc] = *(const float4*)(cp0 + (c << 5));
        *(float4*)&bw[c][lr + 32][lc] = *(const float4*)(cp1 + (c << 5));
        *(float4*)&bw[c][lr + 64][lc] = *(const float4*)(cp2 + (c << 5));
        *(float4*)&ba[c][lr][lc] =
            *(const float4*)(xrow + (size_t)tt * IND + (c << 5));
    };
    stage_gi(0, 0);
    stage_gi(1, 0);
    __syncthreads();

    for (int t = 0; t < T_; ++t) {
        const float* hin  = (t & 1) ? hB : hA;
        float*       hout = (t & 1) ? hA : hB;

        float acc_r[4]  = {0.f, 0.f, 0.f, 0.f};
        float acc_z[4]  = {0.f, 0.f, 0.f, 0.f};
        float acc_ni[4] = {0.f, 0.f, 0.f, 0.f};
        float acc_nh[4] = {0.f, 0.f, 0.f, 0.f};

        // ---- gi phase (h-independent): overlaps the barrier wait ----
        COMPUTE(0, acc_ni)
        COMPUTE(1, acc_ni)

        // ---- wait for h(t-1) published (phase t) ----
        if (t > 0 && tid == 0) {
            while (__hip_atomic_load(release, __ATOMIC_RELAXED,
                                     __HIP_MEMORY_SCOPE_SYSTEM) < t)
                __builtin_amdgcn_s_sleep(2);
        }
        __syncthreads();

        // hprev (used only at gates, latency fully hidden)
        float hp[4];
        #pragma unroll
        for (int i = 0; i < 4; ++i)
            hp[i] = cohLoadF(hin + (size_t)(b0 + bq + (i << 3)) * HID_ + j0 + jj);

        // ---- stage gh chunk 0 into buf0 ----
        {
            float4 w0 = *(const float4*)(wp0);
            float4 w1 = *(const float4*)(wp1);
            float4 w2 = *(const float4*)(wp2);
            float4 a0 = cohLoad4(hin + hrow_off);
            *(float4*)&bw[0][lr     ][lc] = w0;
            *(float4*)&bw[0][lr + 32][lc] = w1;
            *(float4*)&bw[0][lr + 64][lc] = w2;
            *(float4*)&ba[0][lr][lc] = a0;
        }
        __syncthreads();

        // ---- pipelined gh: load chunk m+1 while computing chunk m ----
        #pragma unroll 2
        for (int m = 0; m < 32; ++m) {
            float4 w0, w1, w2, a0;
            if (m < 31) {
                const int o = (m + 1) << 5;
                w0 = *(const float4*)(wp0 + o);
                w1 = *(const float4*)(wp1 + o);
                w2 = *(const float4*)(wp2 + o);
                a0 = cohLoad4(hin + hrow_off + o);
            }
            COMPUTE((m & 1), acc_nh)
            if (m < 31) {
                const int d = (m + 1) & 1;
                *(float4*)&bw[d][lr     ][lc] = w0;
                *(float4*)&bw[d][lr + 32][lc] = w1;
                *(float4*)&bw[d][lr + 64][lc] = w2;
                *(float4*)&ba[d][lr][lc] = a0;
            }
            __syncthreads();
        }

        // ---- gates + h update (coherent stores) ----
        #pragma unroll
        for (int i = 0; i < 4; ++i) {
            float r = sigmoidf_(acc_r[i] + bias_r);
            float z = sigmoidf_(acc_z[i] + bias_z);
            float n = tanhf_(acc_ni[i] + bias_ni + r * (acc_nh[i] + bias_nh));
            cohStoreF(hout + (size_t)(b0 + bq + (i << 3)) * HID_ + j0 + jj,
                      (1.0f - z) * n + z * hp[i]);
        }

        // __syncthreads drains vmcnt(0) on every wave -> all coherent stores
        // are at the L3 coherence point before tid0 publishes the phase.
        __syncthreads();
        if (tid == 0) {
            int old = __hip_atomic_fetch_add(arrive, 1, __ATOMIC_RELAXED,
                                             __HIP_MEMORY_SCOPE_SYSTEM);
            if (old == ((t + 1) << 5) - 1)
                __hip_atomic_store(release, t + 1, __ATOMIC_RELAXED,
                                   __HIP_MEMORY_SCOPE_SYSTEM);
        }
        // stage next step's gi (h-independent) before spinning
        if (t < 255) { stage_gi(0, t + 1); stage_gi(1, t + 1); }
        __syncthreads();
    }
}

// ---------------- fc3: out3 = relu(relu(h) @ fc3_wT + fc3_b) --------------
__global__ __launch_bounds__(256) void k_fc3(
    const float* __restrict__ h, const float* __restrict__ fc3_w,
    const float* __restrict__ fc3_b, float* __restrict__ out3)
{
    const int bt = blockIdx.x >> 3;
    const int dt = blockIdx.x & 7;
    const int b0 = bt << 6;
    const int d0 = dt << 6;
    const int tid = threadIdx.x;
    const int tx = tid & 15, ty = tid >> 4;

    __shared__ float sh_h[64][36];
    __shared__ float sh_w[64][36];

    float acc[4][4] = {};

    const int lr = tid >> 3;
    const int lc = (tid & 7) << 2;

    for (int kk = 0; kk < HID_; kk += 32) {
        #pragma unroll
        for (int p = 0; p < 2; ++p) {
            int row = lr + (p << 5);
            float4 v = *(const float4*)(h + (size_t)(b0 + row) * HID_ + kk + lc);
            v.x = fmaxf(v.x, 0.f); v.y = fmaxf(v.y, 0.f);
            v.z = fmaxf(v.z, 0.f); v.w = fmaxf(v.w, 0.f);
            *(float4*)&sh_h[row][lc] = v;
            *(float4*)&sh_w[row][lc] =
                *(const float4*)(fc3_w + (size_t)(d0 + row) * HID_ + kk + lc);
        }
        __syncthreads();
        #pragma unroll
        for (int k = 0; k < 32; ++k) {
            float hv[4], wv[4];
            #pragma unroll
            for (int i = 0; i < 4; ++i) hv[i] = sh_h[ty + (i << 4)][k];
            #pragma unroll
            for (int q = 0; q < 4; ++q) wv[q] = sh_w[tx + (q << 4)][k];
            #pragma unroll
            for (int i = 0; i < 4; ++i)
                #pragma unroll
                for (int q = 0; q < 4; ++q)
                    acc[i][q] += hv[i] * wv[q];
        }
        __syncthreads();
    }
    #pragma unroll
    for (int i = 0; i < 4; ++i) {
        int b = b0 + ty + (i << 4);
        #pragma unroll
        for (int q = 0; q < 4; ++q) {
            int d = d0 + tx + (q << 4);
            out3[(size_t)b * D2 + d] = fmaxf(acc[i][q] + fc3_b[d], 0.f);
        }
    }
}

// ---------------- copy final h -> hn_out slot of d_out --------------------
__global__ __launch_bounds__(256) void k_copy(
    const float* __restrict__ src, float* __restrict__ dst)
{
    int i = (blockIdx.x * 256 + threadIdx.x) << 2;
    *(float4*)(dst + i) = *(const float4*)(src + i);
}

// ---------------- heads: params[b,o] = out3[b,:]·heads_w[cid[b],o,:]+b ----
__global__ __launch_bounds__(256) void k_heads(
    const float* __restrict__ out3, const int* __restrict__ cult,
    const float* __restrict__ hw, const float* __restrict__ hb,
    float* __restrict__ params)
{
    int b = blockIdx.x;
    int o = threadIdx.x >> 4;
    int l = threadIdx.x & 15;
    int cid = cult[b];
    const float* w = hw + ((size_t)cid * 16 + o) * D2;
    const float* x = out3 + (size_t)b * D2;
    float acc = 0.f;
    #pragma unroll
    for (int m = 0; m < 8; ++m) {
        int d4 = (l + (m << 4)) << 2;
        float4 xv = *(const float4*)(x + d4);
        float4 wv = *(const float4*)(w + d4);
        acc += xv.x * wv.x + xv.y * wv.y + xv.z * wv.z + xv.w * wv.w;
    }
    #pragma unroll
    for (int s = 1; s < 16; s <<= 1)
        acc += __shfl_xor(acc, s, 16);
    if (l == 0)
        params[(size_t)b * 16 + o] = acc + hb[(size_t)cid * 16 + o];
}

extern "C" void kernel_launch(void* const* d_in, const int* in_sizes, int n_in,
                              void* d_out, int out_size, void* d_ws, size_t ws_size,
                              hipStream_t stream)
{
    const float* input = (const float*)d_in[0];
    const float* hn    = (const float*)d_in[1];
    const int*   cult  = (const int*)d_in[2];
    const float* fc1_w = (const float*)d_in[3];
    const float* fc1_b = (const float*)d_in[4];
    const float* fc2_w = (const float*)d_in[5];
    const float* fc2_b = (const float*)d_in[6];
    const float* w_ih  = (const float*)d_in[7];
    const float* w_hh  = (const float*)d_in[8];
    const float* b_ih  = (const float*)d_in[9];
    const float* b_hh  = (const float*)d_in[10];
    const float* fc3_w = (const float*)d_in[11];
    const float* fc3_b = (const float*)d_in[12];
    const float* hw    = (const float*)d_in[13];
    const float* hb    = (const float*)d_in[14];
    float* out = (float*)d_out;

    float* wsf  = (float*)d_ws;
    int*   bar  = (int*)d_ws;            // [0 .. 1024) ints for barriers
    float* W2   = wsf + 1024;            // 1024*64
    float* b2   = W2 + 65536;            // 1024
    float* Wc   = b2 + 1024;             // 3072*64
    float* bc   = Wc + 196608;           // 3072
    float* hA   = bc + 3072;             // 256*1024
    float* hB   = hA + 262144;           // 256*1024
    float* out3 = hB + 262144;           // 256*512

    hipMemsetAsync(d_ws, 0, 4096, stream);
    hipMemcpyAsync(hA, hn, (size_t)262144 * sizeof(float),
                   hipMemcpyDeviceToDevice, stream);

    k_w2<<<256, 256, 0, stream>>>(fc2_w, fc1_w, fc1_b, fc2_b, W2, b2);
    k_wc<<<768, 256, 0, stream>>>(w_ih, W2, b2, b_ih, Wc, bc);
    k_gru<<<256, 256, 0, stream>>>(input, w_hh, b_hh, Wc, bc, hA, hB, bar);
    k_fc3<<<32, 256, 0, stream>>>(hA, fc3_w, fc3_b, out3);
    k_copy<<<256, 256, 0, stream>>>(hA, out + 4096);
    k_heads<<<256, 256, 0, stream>>>(out3, cult, hw, hb, out);
}

// Round 4
// 4557.490 us; speedup vs baseline: 7.0423x; 5.6405x over previous
//
#include <hip/hip_runtime.h>

#define T_   256
#define HID_ 1024
#define D2   512

typedef __attribute__((ext_vector_type(8))) short  short8;
typedef __attribute__((ext_vector_type(8))) __bf16 bf16x8;
typedef __attribute__((ext_vector_type(4))) float  f32x4;

__device__ __forceinline__ float sigmoidf_(float x) {
    return __fdividef(1.0f, 1.0f + __expf(-x));
}
__device__ __forceinline__ float tanhf_(float x) {
    return 1.0f - __fdividef(2.0f, 1.0f + __expf(2.0f * x));
}
__device__ __forceinline__ unsigned short bf16hi(float x) {
    unsigned u = __float_as_uint(x);
    return (unsigned short)((u + 0x7FFFu + ((u >> 16) & 1u)) >> 16);
}
__device__ __forceinline__ float bf2f(unsigned short h) {
    return __uint_as_float((unsigned)h << 16);
}
__device__ __forceinline__ f32x4 mfma_(short8 a, short8 b, f32x4 c) {
    union { short8 s; bf16x8 b; } ua, ub;
    ua.s = a; ub.s = b;
    return __builtin_amdgcn_mfma_f32_16x16x32_bf16(ua.b, ub.b, c, 0, 0, 0);
}

// ---- raw asm memory ops (64-bit VGPR address form: works for divergent ptrs)
__device__ __forceinline__ void gl16(short8& d, const void* p) {
    asm volatile("global_load_dwordx4 %0, %1, off" : "=v"(d) : "v"(p));
}
__device__ __forceinline__ void gl16c(short8& d, const void* p) {
    asm volatile("global_load_dwordx4 %0, %1, off sc0 sc1" : "=v"(d) : "v"(p));
}
__device__ __forceinline__ void gs8c(void* p, unsigned long long v) {
    asm volatile("global_store_dwordx2 %0, %1, off sc0 sc1"
                 :: "v"(p), "v"(v) : "memory");
}
#define WAITV0() asm volatile("s_waitcnt vmcnt(0)" ::: "memory")
#define WAITV2() asm volatile("s_waitcnt vmcnt(2)" ::: "memory")
// waits that "materialize" the A-frag regs so MFMAs can't be hoisted above them
#define WAITV5_TIE(H, L) asm volatile("s_waitcnt vmcnt(5)" : "+v"(H), "+v"(L) :: "memory")
#define WAITV3_TIE(H, L) asm volatile("s_waitcnt vmcnt(3)" : "+v"(H), "+v"(L) :: "memory")
#define WAITV0_TIE(H, L) asm volatile("s_waitcnt vmcnt(0)" : "+v"(H), "+v"(L) :: "memory")
#define ABAR() asm volatile("s_waitcnt lgkmcnt(0)\n\ts_barrier" ::: "memory")

// ---------------- prelim: W2 = fc2_w @ fc1_w, b2 = fc2_w@fc1_b + fc2_b ----
__global__ __launch_bounds__(256) void k_w2(
    const float* __restrict__ fc2_w, const float* __restrict__ fc1_w,
    const float* __restrict__ fc1_b, const float* __restrict__ fc2_b,
    float* __restrict__ W2, float* __restrict__ b2)
{
    int idx = blockIdx.x * 256 + threadIdx.x;   // 0..65535
    int r = idx >> 6, c = idx & 63;
    float acc = 0.f;
    for (int k = 0; k < D2; ++k)
        acc += fc2_w[(size_t)r * D2 + k] * fc1_w[(size_t)k * 64 + c];
    W2[idx] = acc;
    if (c == 0) {
        float a = fc2_b[r];
        for (int k = 0; k < D2; ++k)
            a += fc2_w[(size_t)r * D2 + k] * fc1_b[k];
        b2[r] = a;
    }
}

// -------- prelim: Wc = w_ih @ W2 (bf16 split planes), bc = w_ih@b2 + b_ih --
__global__ __launch_bounds__(256) void k_wc(
    const float* __restrict__ w_ih, const float* __restrict__ W2,
    const float* __restrict__ b2, const float* __restrict__ b_ih,
    unsigned short* __restrict__ wc_hi, unsigned short* __restrict__ wc_lo,
    float* __restrict__ bc)
{
    int idx = blockIdx.x * 256 + threadIdx.x;   // 0..196607
    int r = idx >> 6, c = idx & 63;
    float acc = 0.f;
    for (int k = 0; k < HID_; ++k)
        acc += w_ih[(size_t)r * HID_ + k] * W2[(size_t)k * 64 + c];
    unsigned short h = bf16hi(acc);
    wc_hi[idx] = h;
    wc_lo[idx] = bf16hi(acc - bf2f(h));
    if (c == 0) {
        float a = b_ih[r];
        for (int k = 0; k < HID_; ++k)
            a += w_ih[(size_t)r * HID_ + k] * b2[k];
        bc[r] = a;
    }
}

// ---------------- prelim: split w_hh into bf16 hi/lo planes ----------------
__global__ __launch_bounds__(256) void k_splitw(
    const float* __restrict__ w, unsigned short* __restrict__ hi,
    unsigned short* __restrict__ lo)
{
    int i4 = (blockIdx.x * 256 + threadIdx.x) * 4;
    float4 v = *(const float4*)(w + i4);
    float vv[4] = {v.x, v.y, v.z, v.w};
    unsigned short h4[4], l4[4];
    #pragma unroll
    for (int i = 0; i < 4; ++i) {
        h4[i] = bf16hi(vv[i]);
        l4[i] = bf16hi(vv[i] - bf2f(h4[i]));
    }
    *(unsigned long long*)(hi + i4) =
        (unsigned long long)h4[0] | ((unsigned long long)h4[1] << 16) |
        ((unsigned long long)h4[2] << 32) | ((unsigned long long)h4[3] << 48);
    *(unsigned long long*)(lo + i4) =
        (unsigned long long)l4[0] | ((unsigned long long)l4[1] << 16) |
        ((unsigned long long)l4[2] << 32) | ((unsigned long long)l4[3] << 48);
}

// ------- prelim: h0 -> bf16 split planes in fragment-granule layout --------
// layout: byte = (k>>5)*16384 + b*64 + ((k>>3)&3)*16 + (k&7)*2
__global__ __launch_bounds__(256) void k_split_h0(
    const float* __restrict__ hn, unsigned short* __restrict__ hi,
    unsigned short* __restrict__ lo)
{
    int gid = blockIdx.x * 256 + threadIdx.x;      // 0..32767
    int b = gid >> 7, kseg = gid & 127;
    const float* src = hn + (size_t)b * HID_ + kseg * 8;
    short8 h8, l8;
    #pragma unroll
    for (int i = 0; i < 8; ++i) {
        float v = src[i];
        unsigned short h = bf16hi(v);
        ((short*)&h8)[i] = (short)h;
        ((short*)&l8)[i] = (short)bf16hi(v - bf2f(h));
    }
    size_t off = (size_t)(kseg >> 2) * 8192 + b * 32 + (kseg & 3) * 8; // ushorts
    *(short8*)(hi + off) = h8;
    *(short8*)(lo + off) = l8;
}

// ---------------- main persistent GRU kernel (MFMA split-bf16) -------------
// 256 blocks x 256 threads (1/CU). Block g: ct=g&31 (32 h-cols), bt=g>>5
// (32 batches); g%8==ct%8 pins each col-group's w_hh slice to one XCD L2.
// 4 waves: mh=wid&1 (batch half), kh=wid>>1 (K-chunk parity). Per step:
//   gi = x_t @ Wc^T computed BEFORE the inter-block spin (hides barrier),
//   gh = h @ w_hh^T in 32 K=32 chunks; weights via LDS ring-3 with raw
//   s_barrier + hand vmcnt (loads stay in flight across barriers);
//   h exchanged cross-XCD as bf16 hi/lo planes via sc0 sc1 (1KB/wave loads,
//   coalesced 8B stores) — L1/L2 never invalidated, weights stay cached.
__global__ __launch_bounds__(256, 1) void k_gru(
    const float* __restrict__ input,
    const float* __restrict__ hn,
    const float* __restrict__ b_hh,
    const float* __restrict__ bc,
    const unsigned short* __restrict__ whh_hi,
    const unsigned short* __restrict__ whh_lo,
    const unsigned short* __restrict__ wc_hi,
    const unsigned short* __restrict__ wc_lo,
    unsigned short* __restrict__ hxA_hi, unsigned short* __restrict__ hxA_lo,
    unsigned short* __restrict__ hxB_hi, unsigned short* __restrict__ hxB_lo,
    float* __restrict__ hn_out,
    int* __restrict__ bar)
{
    const int g = blockIdx.x, ct = g & 31, bt = g >> 5;
    const int j0 = ct << 5, b0 = bt << 5;
    const int tid = threadIdx.x, lane = tid & 63, wid = tid >> 6;
    const int mh = wid & 1, kh = wid >> 1;
    const int l15 = lane & 15, quad = lane >> 4;

    __shared__ short smB[23040];              // 3 ring bufs x 7680 shorts
    float* smF = (float*)smB;                 // C-dump alias (post-K-loop)
    const int SIN_ = 4672, SHN_ = 6784;

    // ---- B staging descriptors: 3 x 16B segs per thread per K32 chunk ----
    const int t7 = tid & 127, pl = tid >> 7;
    const unsigned short* wsrc = pl ? whh_lo : whh_hi;
    const unsigned short* csrc = pl ? wc_lo : wc_hi;
    const char* wB[3]; const char* cB[3]; int lo_[3];
    #pragma unroll
    for (int i = 0; i < 3; ++i) {
        int sid = t7 + (i << 7);
        int n = sid >> 2, ss = sid & 3;
        int grow = (n >> 5) * HID_ + j0 + (n & 31);
        wB[i] = (const char*)wsrc + (size_t)grow * 2048u + (size_t)ss * 16u;
        cB[i] = (const char*)csrc + (size_t)grow * 128u + (size_t)ss * 16u;
        lo_[i] = (pl * 96 + n) * 40 + ss * 8;
    }
    const int foff = l15 * 40 + quad * 8;     // B-frag read offset (shorts)
    const size_t aoff = (size_t)((b0 + mh * 16 + l15) * 64 + quad * 16);
    const char* aAh = (const char*)hxA_hi + aoff;
    const char* aAl = (const char*)hxA_lo + aoff;
    const char* aBh = (const char*)hxB_hi + aoff;
    const char* aBl = (const char*)hxB_lo + aoff;
    const float* xrow = input + (size_t)(b0 + mh * 16 + l15) * (T_ * 64)
                              + kh * 32 + quad * 8;

    // ---- gate-phase statics: thread owns (b = b0+gb, j = j0+gj4..+3) -----
    const int gb = tid >> 3, gj4 = (tid & 7) << 2;
    float hreg[4], br[4], bz[4], bni[4], bnh[4];
    #pragma unroll
    for (int i = 0; i < 4; ++i) {
        int j = j0 + gj4 + i;
        hreg[i] = hn[(size_t)(b0 + gb) * HID_ + j];
        br[i]  = bc[j] + b_hh[j];
        bz[i]  = bc[1024 + j] + b_hh[1024 + j];
        bni[i] = bc[2048 + j];
        bnh[i] = b_hh[2048 + j];
    }
    const size_t hoff = (size_t)(ct * 16384 + (b0 + gb) * 64 + gj4 * 2);
    char* sAh = (char*)hxA_hi + hoff; char* sAl = (char*)hxA_lo + hoff;
    char* sBh = (char*)hxB_hi + hoff; char* sBl = (char*)hxB_lo + hoff;
    const int g73 = gb * 73, g33 = gb * 33;

    int* arrive  = bar + bt * 128;
    int* release = bar + bt * 128 + 32;

    short8 bp[2][3];   // weight payload, set = chunk&1
    short8 ab[2][2];   // A-frag banks [bank][hi/lo]
    f32x4 acc[6], acci[2];

#define GH_CHUNK(RB, AH, AL)                                                  \
  { _Pragma("unroll")                                                         \
    for (int nt = 0; nt < 6; ++nt) {                                          \
        short8 bh_ = *(const short8*)(smB + (RB) + nt * 640 + foff);          \
        short8 bl_ = *(const short8*)(smB + (RB) + 3840 + nt * 640 + foff);   \
        f32x4 v_ = mfma_(AH, bh_, acc[nt]);                                   \
        v_ = mfma_(AH, bl_, v_);                                              \
        v_ = mfma_(AL, bh_, v_);                                              \
        acc[nt] = v_; } }

    #pragma unroll 1
    for (int t = 0; t < 256; ++t) {
        const char* rh = (t & 1) ? aBh : aAh;   // read planes (h in)
        const char* rl = (t & 1) ? aBl : aAl;
        char* wh = (t & 1) ? sAh : sBh;         // write planes (h out)
        char* wl = (t & 1) ? sAl : sBl;

        // ---- gi staging (h-independent; overlaps the coming spin) ----
        short8 gp[2][3];
        #pragma unroll
        for (int c = 0; c < 2; ++c)
            #pragma unroll
            for (int i = 0; i < 3; ++i)
                gl16(gp[c][i], cB[i] + c * 64);
        // x_t load + split (plain cached loads; compiler-managed waits)
        float xv[8];
        *(float4*)&xv[0] = *(const float4*)(xrow + (size_t)t * 64);
        *(float4*)&xv[4] = *(const float4*)(xrow + (size_t)t * 64 + 4);
        short8 xa_hi, xa_lo;
        #pragma unroll
        for (int i = 0; i < 8; ++i) {
            unsigned short h = bf16hi(xv[i]);
            ((short*)&xa_hi)[i] = (short)h;
            ((short*)&xa_lo)[i] = (short)bf16hi(xv[i] - bf2f(h));
        }
        WAITV0();
        #pragma unroll
        for (int c = 0; c < 2; ++c)
            #pragma unroll
            for (int i = 0; i < 3; ++i)
                *(short8*)(smB + c * 7680 + lo_[i]) = gp[c][i];
        // issue w_hh chunks 0,1 (pre-spin is safe: weights are step-invariant)
        #pragma unroll
        for (int c = 0; c < 2; ++c)
            #pragma unroll
            for (int i = 0; i < 3; ++i)
                gl16(bp[c][i], wB[i] + c * 64);
        ABAR();
        // ---- gi compute (Wc chunk = kh), inits accumulators ----
        {
            const int rb = kh * 7680;
            #pragma unroll
            for (int nt = 0; nt < 6; ++nt) {
                short8 bh_ = *(const short8*)(smB + rb + nt * 640 + foff);
                short8 bl_ = *(const short8*)(smB + rb + 3840 + nt * 640 + foff);
                f32x4 z = {0.f, 0.f, 0.f, 0.f};
                f32x4 v = mfma_(xa_hi, bh_, z);
                v = mfma_(xa_hi, bl_, v);
                v = mfma_(xa_lo, bh_, v);
                if (nt < 4) { acc[nt] = v; }
                else { acci[nt - 4] = v; acc[nt] = z; }
            }
        }
        // ---- wait for h(t) published ----
        if (t > 0 && tid == 0) {
            while (__hip_atomic_load(release, __ATOMIC_RELAXED,
                                     __HIP_MEMORY_SCOPE_SYSTEM) < t)
                __builtin_amdgcn_s_sleep(4);
        }
        ABAR();
        // ---- prologue: A(chunk kh) into bank1; stage w chunk 0 -> buf 2 ----
        gl16c(ab[1][0], rh + (size_t)kh * 16384);
        gl16c(ab[1][1], rl + (size_t)kh * 16384);
        WAITV2();
        #pragma unroll
        for (int i = 0; i < 3; ++i)
            *(short8*)(smB + 15360 + lo_[i]) = bp[0][i];
        // ---- gh pipeline: ring-3, loads 2 chunks deep across barriers ----
        #pragma unroll
        for (int c = 2; c <= 31; ++c) {
            const int sN  = c & 1;
            const int bkC = (c >> 1) & 1;
            const int bkN = ((c + 1) >> 1) & 1;
            const int wofs = ((c + 1) % 3) * 7680;
            const int rofs = (c % 3) * 7680;
            if ((c & 1) == kh) {
                #pragma unroll
                for (int i = 0; i < 3; ++i)
                    gl16(bp[sN][i], wB[i] + c * 64);
                gl16c(ab[bkC ^ 1][0], rh + (size_t)c * 16384);
                gl16c(ab[bkC ^ 1][1], rl + (size_t)c * 16384);
                WAITV5_TIE(ab[bkC][0], ab[bkC][1]);
            } else {
                #pragma unroll
                for (int i = 0; i < 3; ++i)
                    gl16(bp[sN][i], wB[i] + c * 64);
                WAITV3_TIE(ab[bkN][0], ab[bkN][1]);
            }
            #pragma unroll
            for (int i = 0; i < 3; ++i)
                *(short8*)(smB + wofs + lo_[i]) = bp[sN ^ 1][i];
            ABAR();
            if ((c & 1) == kh) GH_CHUNK(rofs, ab[bkC][0], ab[bkC][1]);
        }
        // epilogue: chunks 30 (kh=0, buf 2) / 31 (kh=1, buf 0)
        WAITV0_TIE(ab[0][0], ab[0][1]);
        #pragma unroll
        for (int i = 0; i < 3; ++i)
            *(short8*)(smB + lo_[i]) = bp[1][i];          // chunk 31 -> buf 0
        ABAR();
        if (kh == 0) GH_CHUNK(15360, ab[0][0], ab[0][1]);
        if (kh == 1) GH_CHUNK(0,     ab[0][0], ab[0][1]);
        __syncthreads();
        // ---- dump C fragments (aliased over ring bufs) ----
        {
            const int row = mh * 16 + quad * 4;
            #pragma unroll
            for (int nt = 0; nt < 4; ++nt)
                #pragma unroll
                for (int r = 0; r < 4; ++r)
                    smF[kh * 2336 + (row + r) * 73 + nt * 16 + l15] = acc[nt][r];
            #pragma unroll
            for (int jn = 0; jn < 2; ++jn)
                #pragma unroll
                for (int r = 0; r < 4; ++r) {
                    smF[SHN_ + kh * 1056 + (row + r) * 33 + jn * 16 + l15] = acc[4 + jn][r];
                    smF[SIN_ + kh * 1056 + (row + r) * 33 + jn * 16 + l15] = acci[jn][r];
                }
        }
        __syncthreads();
        // ---- gate phase: thread owns (gb, gj4..+3); hprev in registers ----
        unsigned short ph4[4], pl4[4];
        #pragma unroll
        for (int i = 0; i < 4; ++i) {
            int cl = gj4 + i;
            float rp = smF[g73 + cl] + smF[2336 + g73 + cl] + br[i];
            float zp = smF[g73 + 32 + cl] + smF[2336 + g73 + 32 + cl] + bz[i];
            float ip = smF[SIN_ + g33 + cl] + smF[SIN_ + 1056 + g33 + cl] + bni[i];
            float hp = smF[SHN_ + g33 + cl] + smF[SHN_ + 1056 + g33 + cl] + bnh[i];
            float rr = sigmoidf_(rp);
            float zz = sigmoidf_(zp);
            float nn = tanhf_(ip + rr * hp);
            float hv = (1.0f - zz) * nn + zz * hreg[i];
            hreg[i] = hv;
            unsigned short hh = bf16hi(hv);
            ph4[i] = hh;
            pl4[i] = bf16hi(hv - bf2f(hh));
        }
        unsigned long long pk_hi =
            (unsigned long long)ph4[0] | ((unsigned long long)ph4[1] << 16) |
            ((unsigned long long)ph4[2] << 32) | ((unsigned long long)ph4[3] << 48);
        unsigned long long pk_lo =
            (unsigned long long)pl4[0] | ((unsigned long long)pl4[1] << 16) |
            ((unsigned long long)pl4[2] << 32) | ((unsigned long long)pl4[3] << 48);
        gs8c(wh, pk_hi);
        gs8c(wl, pk_lo);
        if (t == 255) {
            #pragma unroll
            for (int i = 0; i < 4; ++i)
                hn_out[(size_t)(b0 + gb) * HID_ + j0 + gj4 + i] = hreg[i];
        }
        WAITV0();           // h-plane stores at coherence point
        __syncthreads();    // whole block done
        if (t < 255 && tid == 0) {
            int old = __hip_atomic_fetch_add(arrive, 1, __ATOMIC_RELAXED,
                                             __HIP_MEMORY_SCOPE_SYSTEM);
            if (old == ((t + 1) << 5) - 1)
                __hip_atomic_store(release, t + 1, __ATOMIC_RELAXED,
                                   __HIP_MEMORY_SCOPE_SYSTEM);
        }
    }
#undef GH_CHUNK
}

// ---------------- fc3: out3 = relu(relu(h) @ fc3_wT + fc3_b) --------------
__global__ __launch_bounds__(256) void k_fc3(
    const float* __restrict__ h, const float* __restrict__ fc3_w,
    const float* __restrict__ fc3_b, float* __restrict__ out3)
{
    const int bt = blockIdx.x >> 3;
    const int dt = blockIdx.x & 7;
    const int b0 = bt << 6;
    const int d0 = dt << 6;
    const int tid = threadIdx.x;
    const int tx = tid & 15, ty = tid >> 4;

    __shared__ float sh_h[64][36];
    __shared__ float sh_w[64][36];

    float acc[4][4] = {};
    const int lr = tid >> 3;
    const int lc = (tid & 7) << 2;

    for (int kk = 0; kk < HID_; kk += 32) {
        #pragma unroll
        for (int p = 0; p < 2; ++p) {
            int row = lr + (p << 5);
            float4 v = *(const float4*)(h + (size_t)(b0 + row) * HID_ + kk + lc);
            v.x = fmaxf(v.x, 0.f); v.y = fmaxf(v.y, 0.f);
            v.z = fmaxf(v.z, 0.f); v.w = fmaxf(v.w, 0.f);
            *(float4*)&sh_h[row][lc] = v;
            *(float4*)&sh_w[row][lc] =
                *(const float4*)(fc3_w + (size_t)(d0 + row) * HID_ + kk + lc);
        }
        __syncthreads();
        #pragma unroll
        for (int k = 0; k < 32; ++k) {
            float hv[4], wv[4];
            #pragma unroll
            for (int i = 0; i < 4; ++i) hv[i] = sh_h[ty + (i << 4)][k];
            #pragma unroll
            for (int q = 0; q < 4; ++q) wv[q] = sh_w[tx + (q << 4)][k];
            #pragma unroll
            for (int i = 0; i < 4; ++i)
                #pragma unroll
                for (int q = 0; q < 4; ++q)
                    acc[i][q] += hv[i] * wv[q];
        }
        __syncthreads();
    }
    #pragma unroll
    for (int i = 0; i < 4; ++i) {
        int b = b0 + ty + (i << 4);
        #pragma unroll
        for (int q = 0; q < 4; ++q) {
            int d = d0 + tx + (q << 4);
            out3[(size_t)b * D2 + d] = fmaxf(acc[i][q] + fc3_b[d], 0.f);
        }
    }
}

// ---------------- heads: params[b,o] = out3[b,:]·heads_w[cid[b],o,:]+b ----
__global__ __launch_bounds__(256) void k_heads(
    const float* __restrict__ out3, const int* __restrict__ cult,
    const float* __restrict__ hw, const float* __restrict__ hb,
    float* __restrict__ params)
{
    int b = blockIdx.x;
    int o = threadIdx.x >> 4;
    int l = threadIdx.x & 15;
    int cid = cult[b];
    const float* w = hw + ((size_t)cid * 16 + o) * D2;
    const float* x = out3 + (size_t)b * D2;
    float acc = 0.f;
    #pragma unroll
    for (int m = 0; m < 8; ++m) {
        int d4 = (l + (m << 4)) << 2;
        float4 xv = *(const float4*)(x + d4);
        float4 wv = *(const float4*)(w + d4);
        acc += xv.x * wv.x + xv.y * wv.y + xv.z * wv.z + xv.w * wv.w;
    }
    #pragma unroll
    for (int s = 1; s < 16; s <<= 1)
        acc += __shfl_xor(acc, s, 16);
    if (l == 0)
        params[(size_t)b * 16 + o] = acc + hb[(size_t)cid * 16 + o];
}

extern "C" void kernel_launch(void* const* d_in, const int* in_sizes, int n_in,
                              void* d_out, int out_size, void* d_ws, size_t ws_size,
                              hipStream_t stream)
{
    const float* input = (const float*)d_in[0];
    const float* hn    = (const float*)d_in[1];
    const int*   cult  = (const int*)d_in[2];
    const float* fc1_w = (const float*)d_in[3];
    const float* fc1_b = (const float*)d_in[4];
    const float* fc2_w = (const float*)d_in[5];
    const float* fc2_b = (const float*)d_in[6];
    const float* w_ih  = (const float*)d_in[7];
    const float* w_hh  = (const float*)d_in[8];
    const float* b_ih  = (const float*)d_in[9];
    const float* b_hh  = (const float*)d_in[10];
    const float* fc3_w = (const float*)d_in[11];
    const float* fc3_b = (const float*)d_in[12];
    const float* hw    = (const float*)d_in[13];
    const float* hb    = (const float*)d_in[14];
    float* out = (float*)d_out;
    float* hn_out = out + 4096;          // params 256*16, then hn 256*1024

    char* ws = (char*)d_ws;
    int*   bar    = (int*)ws;                                   // 4 KB
    float* W2     = (float*)(ws + 4096);                        // 256 KB
    float* b2     = (float*)(ws + 266240);
    float* bc     = (float*)(ws + 270336);
    unsigned short* whh_hi = (unsigned short*)(ws + 282624);    // 6 MB
    unsigned short* whh_lo = (unsigned short*)(ws + 282624 + 6291456);
    unsigned short* wc_hi  = (unsigned short*)(ws + 12865536);
    unsigned short* wc_lo  = (unsigned short*)(ws + 13258752);
    unsigned short* hxA_hi = (unsigned short*)(ws + 13651968);
    unsigned short* hxA_lo = (unsigned short*)(ws + 14176256);
    unsigned short* hxB_hi = (unsigned short*)(ws + 14700544);
    unsigned short* hxB_lo = (unsigned short*)(ws + 15224832);
    float* out3   = (float*)(ws + 15749120);                    // 512 KB

    hipMemsetAsync(bar, 0, 4096, stream);
    k_w2<<<256, 256, 0, stream>>>(fc2_w, fc1_w, fc1_b, fc2_b, W2, b2);
    k_wc<<<768, 256, 0, stream>>>(w_ih, W2, b2, b_ih, wc_hi, wc_lo, bc);
    k_splitw<<<3072, 256, 0, stream>>>(w_hh, whh_hi, whh_lo);
    k_split_h0<<<128, 256, 0, stream>>>(hn, hxA_hi, hxA_lo);
    k_gru<<<256, 256, 0, stream>>>(input, hn, b_hh, bc,
                                   whh_hi, whh_lo, wc_hi, wc_lo,
                                   hxA_hi, hxA_lo, hxB_hi, hxB_lo,
                                   hn_out, bar);
    k_fc3<<<32, 256, 0, stream>>>(hn_out, fc3_w, fc3_b, out3);
    k_heads<<<256, 256, 0, stream>>>(out3, cult, hw, hb, out);
}